// Round 12
// baseline (223.967 us; speedup 1.0000x reference)
//
#include <hip/hip_runtime.h>

// SSIM loss via separable 11-tap Gaussian — R21: R20's persistent-pipelined
// experiment DE-CONFOUNDED. R20 regressed (122us) because the rolled tile
// loop + reference-captured float4 prefetch + runtime buf index sent the
// prefetch registers to SCRATCH (WRITE_SIZE 0.38MB -> 46MB = the smoking
// gun; guide rule #20). The convoy theory was never tested. R21 fixes:
//  - #pragma unroll on the tile loop: buf indices compile-time, prefetch
//    float4s are iteration-scoped SSA (load-top -> stage-bottom, same
//    iteration). No runtime-indexed aggregates anywhere.
//  - Staging addressing hoisted: per-thread (r,c4), global off go_j, LDS
//    off wo_j computed ONCE; per tile address = ybase + xoff + go_j.
//  - __launch_bounds__(256,4): VGPR cap 128 (est peak ~80), no spill.
// Structure (R19-verified compute, unchanged): 1536 persistent blocks x
// TPB=8 x-adjacent 32x32 tiles (same strip -> halo L2 hits), LDS double
// buffer, per-iter {load(i+1) -> compute(i) -> stage(i+1) -> ldsBarrier}.
// Compute: wave owns 16x16 out tile; A-op = 4x ds_read_b128 (SXW=28,
// 16B-aligned, 2-way max); horizontal mfma_16x16x32 (bt[e]=g[8lg+e-lm-3]);
// B-phase D-layout == K=16 B-op fragment -> vertical = 2 chained
// mfma_16x16x16f16 (ca_b[e]=g[16b+4lg+e-lm-3]); 5 quantities.
// Pre-committed readings: WRITE_SIZE must be ~0.4MB (else still
// confounded); ~32-40us => convoy confirmed; ~50us clean => wall ->
// roofline call next round.
// Reduction history (do NOT re-fuse): R13 fences -> 9x; R14 same-line
// relaxed atomics -> 3x (XCD ping-pong). Two-kernel scheme stands.
// Numerics: f16 data/taps (center-corrected), f32 accum -> absmax 0.0039.

typedef __fp16 f16x8 __attribute__((ext_vector_type(8)));
typedef __fp16 f16x4 __attribute__((ext_vector_type(4)));
typedef float  f32x4 __attribute__((ext_vector_type(4)));
typedef unsigned u32x2 __attribute__((ext_vector_type(2)));
typedef unsigned u32x4 __attribute__((ext_vector_type(4)));

__device__ __forceinline__ unsigned pk2(float a, float b) {
    return __builtin_bit_cast(unsigned, __builtin_amdgcn_cvt_pkrtz(a, b));
}
__device__ __forceinline__ f32x4 mfmaB(f16x8 a, f16x8 b, f32x4 c) {
    return __builtin_amdgcn_mfma_f32_16x16x32_f16(a, b, c, 0, 0, 0);
}
__device__ __forceinline__ f32x4 mfmaC(f16x4 a, f16x4 b, f32x4 c) {
    return __builtin_amdgcn_mfma_f32_16x16x16f16(a, b, c, 0, 0, 0);
}
// LDS-only barrier: orders LDS across waves WITHOUT draining vmcnt.
__device__ __forceinline__ void ldsBarrier() {
    asm volatile("s_waitcnt lgkmcnt(0)\n\ts_barrier" ::: "memory");
}

#define SXW 28   // staged words/row; mult of 4 -> all b128 reads 16B-aligned
#define TPB 8    // tiles per block (one 8-tile x-strip half)

__global__ __launch_bounds__(256, 4) void ssim_main(
    const float* __restrict__ xg, const float* __restrict__ yg,
    const float* __restrict__ w2d, float* __restrict__ part)
{
    __shared__ __align__(16) unsigned sx[2][48 * SXW];  // 2 x 5376 B
    __shared__ __align__(16) unsigned sy[2][48 * SXW];  // 2 x 5376 B
    __shared__ unsigned tbp[64];
    __shared__ float gsf[11];
    __shared__ float wred[4];

    const int tid = threadIdx.x;
    const int nblk = (int)gridDim.x;            // 1536, %8 == 0
    const int bid = (int)blockIdx.x;
    const int swzb = (bid & 7) * (nblk >> 3) + (bid >> 3);
    const int tbase = swzb * TPB;               // 8 x-adjacent tiles
    const int tz = tbase >> 8, tyy = (tbase >> 4) & 15, txb = tbase & 15;
    const float* __restrict__ xp = xg + (size_t)tz * (512 * 512);
    const float* __restrict__ yp = yg + (size_t)tz * (512 * 512);
    const int ybase = (32 * tyy - 8) * 512;
    const bool yok = (tyy > 0) & (tyy < 15);

    // Hoisted staging geometry: items it0=tid, it1=tid+256, it2=tid+512
    // (576 = 48 rows x 12 float4-groups; it2 only for tid<64).
    const bool h2 = tid < 64;
    const int it1 = tid + 256, it2 = tid + 512;
    const int r0 = tid / 12, c0 = tid - 12 * r0;
    const int r1 = it1 / 12, c1 = it1 - 12 * r1;
    const int r2 = it2 / 12, c2 = it2 - 12 * r2;
    const int go0 = r0 * 512 + 4 * c0, wo0 = r0 * SXW + 2 * c0;
    const int go1 = r1 * 512 + 4 * c1, wo1 = r1 * SXW + 2 * c1;
    const int go2 = r2 * 512 + 4 * c2, wo2 = r2 * SXW + 2 * c2;

    // One item load (gr checks only on border tiles; block-uniform branch).
    auto ldone = [&](int xoff, bool inter, int go, int r, int c4,
                     float4& vx, float4& vy) {
        if (inter) {
            const int o = ybase + xoff + go;
            vx = *(const float4*)&xp[o];
            vy = *(const float4*)&yp[o];
        } else {
            const int gr = 32 * tyy - 8 + r;
            const bool rok = (unsigned)gr < 512u;
            const int gc0 = xoff + 4 * c4;
            float tx4[4], ty4[4];
            #pragma unroll
            for (int j = 0; j < 4; ++j) {
                const int gc = gc0 + j;
                const bool ok = rok & ((unsigned)gc < 512u);
                const int o = ok ? (gr * 512 + gc) : 0;
                tx4[j] = ok ? xp[o] : 0.f;
                ty4[j] = ok ? yp[o] : 0.f;
            }
            vx = make_float4(tx4[0], tx4[1], tx4[2], tx4[3]);
            vy = make_float4(ty4[0], ty4[1], ty4[2], ty4[3]);
        }
    };
    auto st1 = [&](unsigned* s, int wo, const float4& v) {
        *(uint2*)&s[wo] = make_uint2(pk2(v.x, v.y), pk2(v.z, v.w));
    };

    // Tap table, built ENTIRELY by wave 0 (intra-wave LDS ordering).
    // 1D kernel = row sums of outer(g,g); f16 taps with center correction;
    // tbp[i] = (tap(i-19), tap(i-18)) packed f16x2.
    if (tid < 11) {
        float s = 0.0f;
        #pragma unroll
        for (int j = 0; j < 11; ++j) s += w2d[tid * 11 + j];
        gsf[tid] = s;
    }
    if (tid < 64) {
        float ssum = 0.0f;
        #pragma unroll
        for (int k = 0; k < 11; ++k)
            if (k != 5) ssum += (float)(__fp16)gsf[k];
        const __fp16 cc = (__fp16)(1.0f - ssum);
        auto tap = [&](int t) -> __fp16 {
            if ((unsigned)t > 10u) return (__fp16)0.f;
            return (t == 5) ? cc : (__fp16)gsf[t];
        };
        const int t = tid - 19;
        const unsigned short lo = __builtin_bit_cast(unsigned short, tap(t));
        const unsigned short hi = __builtin_bit_cast(unsigned short, tap(t + 1));
        tbp[tid] = (unsigned)lo | ((unsigned)hi << 16);
    }

    // Prologue: tile 0 into buf 0.
    {
        const int tx = txb;
        const int xoff = 32 * tx - 8;
        const bool inter = yok & (tx > 0) & (tx < 15);
        float4 px0, py0, px1, py1, px2, py2;
        ldone(xoff, inter, go0, r0, c0, px0, py0);
        ldone(xoff, inter, go1, r1, c1, px1, py1);
        if (h2) ldone(xoff, inter, go2, r2, c2, px2, py2);
        st1(sx[0], wo0, px0); st1(sy[0], wo0, py0);
        st1(sx[0], wo1, px1); st1(sy[0], wo1, py1);
        if (h2) { st1(sx[0], wo2, px2); st1(sy[0], wo2, py2); }
    }
    ldsBarrier();                               // staging + tbp visible

    const int lane = tid & 63, wv = tid >> 6;
    const int lm = lane & 15, lg = lane >> 4;
    const int wr = wv >> 1, wc = wv & 1;

    // Tap fragments (verified R18/R19): B bt[e]=g[8lg+e-lm-3]; C band b
    // ca_b[e]=g[16b+4lg+e-lm-3]. Pair indices in [1,46].
    f16x8 bt;
    f16x4 ca0, ca1;
    {
        const int ib = 8 * lg - lm + 16;
        const u32x4 wb = {tbp[ib], tbp[ib + 2], tbp[ib + 4], tbp[ib + 6]};
        bt = __builtin_bit_cast(f16x8, wb);
        const int ic = 4 * lg - lm + 16;
        const u32x2 w0 = {tbp[ic], tbp[ic + 2]};
        const u32x2 w1 = {tbp[ic + 16], tbp[ic + 18]};
        ca0 = __builtin_bit_cast(f16x4, w0);
        ca1 = __builtin_bit_cast(f16x4, w1);
    }

    const int rbase = (16 * wr + lm) * SXW + 8 * wc + 4 * lg;
    const f32x4 z4 = {0.f, 0.f, 0.f, 0.f};
    const float C1 = 1e-4f, C2 = 9e-4f;
    float lsum = 0.0f;

    // Fully-unrolled pipeline: load(i+1) || compute(i) ; stage(i+1) ; bar.
    #pragma unroll
    for (int i = 0; i < TPB; ++i) {
        const int cur = i & 1;                  // compile-time under unroll
        float4 px0, py0, px1, py1, px2, py2;    // iteration-scoped SSA
        if (i + 1 < TPB) {
            const int tx = txb + i + 1;
            const int xoff = 32 * tx - 8;
            const bool inter = yok & (tx > 0) & (tx < 15);
            ldone(xoff, inter, go0, r0, c0, px0, py0);
            ldone(xoff, inter, go1, r1, c1, px1, py1);
            if (h2) ldone(xoff, inter, go2, r2, c2, px2, py2);
        }

        // Compute tile i from buf[cur].
        {
            const unsigned* __restrict__ sxc = sx[cur];
            const unsigned* __restrict__ syc = sy[cur];
            const f16x8 xd0 = __builtin_bit_cast(f16x8, *(const u32x4*)&sxc[rbase]);
            const f16x8 xd1 = __builtin_bit_cast(f16x8, *(const u32x4*)&sxc[rbase + 16 * SXW]);
            const f16x8 yd0 = __builtin_bit_cast(f16x8, *(const u32x4*)&syc[rbase]);
            const f16x8 yd1 = __builtin_bit_cast(f16x8, *(const u32x4*)&syc[rbase + 16 * SXW]);

            f32x4 acc[5];
            #pragma unroll
            for (int q = 0; q < 5; ++q) {
                f16x8 a0, a1;
                if (q == 0)      { a0 = xd0;       a1 = xd1; }
                else if (q == 1) { a0 = yd0;       a1 = yd1; }
                else if (q == 2) { a0 = xd0 * xd0; a1 = xd1 * xd1; }
                else if (q == 3) { a0 = yd0 * yd0; a1 = yd1 * yd1; }
                else             { a0 = xd0 * yd0; a1 = xd1 * yd1; }
                const f32x4 d0 = mfmaB(a0, bt, z4);
                const f32x4 d1 = mfmaB(a1, bt, z4);
                const u32x2 h0 = {pk2(d0[0], d0[1]), pk2(d0[2], d0[3])};
                const u32x2 h1 = {pk2(d1[0], d1[1]), pk2(d1[2], d1[3])};
                const f32x4 p0 = mfmaC(ca0, __builtin_bit_cast(f16x4, h0), z4);
                acc[q]         = mfmaC(ca1, __builtin_bit_cast(f16x4, h1), p0);
            }

            #pragma unroll
            for (int r = 0; r < 4; ++r) {
                const float mx = acc[0][r], my = acc[1][r];
                const float exx = acc[2][r], eyy = acc[3][r];
                const float exy = acc[4][r];
                const float mx2 = mx * mx, my2 = my * my, mxy = mx * my;
                const float vx = exx - mx2, vy = eyy - my2, vxy = exy - mxy;
                const float num = (2.0f * mxy + C1) * (2.0f * vxy + C2);
                const float den = (mx2 + my2 + C1) * (vx + vy + C2) + 1e-12f;
                lsum = fmaf(num, __builtin_amdgcn_rcpf(den), lsum);
            }
        }

        if (i + 1 < TPB) {                      // stage tile i+1 -> buf^1
            unsigned* bx = sx[cur ^ 1];
            unsigned* by = sy[cur ^ 1];
            st1(bx, wo0, px0); st1(by, wo0, py0);
            st1(bx, wo1, px1); st1(by, wo1, py1);
            if (h2) { st1(bx, wo2, px2); st1(by, wo2, py2); }
        }
        ldsBarrier();   // compute(cur) reads done; stage(cur^1) visible
    }

    // Wave reduce -> 4-float LDS -> one plain store per block.
    #pragma unroll
    for (int off = 32; off > 0; off >>= 1)
        lsum += __shfl_down(lsum, off, 64);
    if ((tid & 63) == 0) wred[tid >> 6] = lsum;
    ldsBarrier();
    if (tid == 0)
        part[bid] = wred[0] + wred[1] + wred[2] + wred[3];
}

__global__ __launch_bounds__(1024) void ssim_reduce(
    const float* __restrict__ part, float* __restrict__ out,
    int n, float invN)
{
    __shared__ float wred[16];
    float s = 0.0f;
    for (int i = threadIdx.x; i < n; i += 1024) s += part[i];
    #pragma unroll
    for (int off = 32; off > 0; off >>= 1)
        s += __shfl_down(s, off, 64);
    if ((threadIdx.x & 63) == 0) wred[threadIdx.x >> 6] = s;
    __syncthreads();
    if (threadIdx.x == 0) {
        float tot = 0.0f;
        #pragma unroll
        for (int w = 0; w < 16; ++w) tot += wred[w];
        out[0] = 1.0f - tot * invN;
    }
}

extern "C" void kernel_launch(void* const* d_in, const int* in_sizes, int n_in,
                              void* d_out, int out_size, void* d_ws, size_t ws_size,
                              hipStream_t stream) {
    const float* x   = (const float*)d_in[0];
    const float* y   = (const float*)d_in[1];
    const float* w2d = (const float*)d_in[2];  // (3,1,11,11); channels identical
    float* out  = (float*)d_out;
    float* part = (float*)d_ws;                // 1536 floats = 6 KB

    const int H = 512, W = 512;
    const int total = in_sizes[0];              // 16*3*512*512
    const int Z = total / (H * W);              // 48

    // 48 images x 256 tiles(32x32) = 12288 tiles = 1536 blocks x 8 tiles.
    const int nblk = Z * 256 / TPB;
    ssim_main<<<dim3(nblk), 256, 0, stream>>>(x, y, w2d, part);

    const float invN = 1.0f / (float)total;
    ssim_reduce<<<1, 1024, 0, stream>>>(part, out, nblk, invN);
}